// Round 8
// baseline (520.960 us; speedup 1.0000x reference)
//
#include <hip/hip_runtime.h>

// ChainMessagePassing: out[n] = sum over edges with dst==n of x[src], two edge lists.
// x: [N=100000, 64] fp32; indices: [2, E=3200000] (src row 0, dst row 1), int64/int32.
//
// R8: single-level exact-offset partition (hist -> scan -> scatter, runs ~10
// records with padded cursors) + merge-walk gather: per 64-node bucket, LDS
// counting sort by (dst_local<<4)|src_slab, then each 16-lane group walks its
// FOUR dl-ranges concurrently (4 row-loads in flight, direct register adds,
// no routing, no short-run restarts). Slab-minor order preserves the
// device-wide sliding L2 window (R7 verified: FETCH 652->196 MB).

static constexpr int D = 64;
static constexpr int Q = 16;            // float4 quads per row
static constexpr int NPB = 64;          // nodes per bucket
static constexpr int NPB_SHIFT = 6;
static constexpr int SLABS = 16;        // src slabs in gather sort key
static constexpr int NBIN = NPB * SLABS;  // 1024 sort bins
static constexpr int CHUNK = 16384;     // edges per scatter block
static constexpr int CH = 8192;         // records per gather sort chunk (32 KB)
static constexpr int CURPAD = 16;       // ints per padded cursor (64B line)

// ---- index dtype sniffer: int64 nonneg <2^31 has all-zero odd dwords ----
__global__ void detect_idx_dtype(const int* __restrict__ w, int* __restrict__ flag) {
    int tid = threadIdx.x;  // one wave
    int v = w[2 * tid + 1];
    unsigned long long m = __ballot(v != 0);
    if (tid == 0) *flag = (m == 0ULL) ? 1 : 0;
}

__device__ __forceinline__ int load_idx(const void* idx, long long i, int is64) {
    return is64 ? (int)((const long long*)idx)[i] : ((const int*)idx)[i];
}

// ---- phase 1: fine-bucket histogram (LDS-aggregated) ----
__global__ __launch_bounds__(256) void hist_kernel(
        const void* __restrict__ up, const void* __restrict__ down,
        int* __restrict__ fineCnt, const int* __restrict__ flag, int E, int NB) {
    extern __shared__ int lcnt[];
    const int is64 = *flag;
    for (int i = threadIdx.x; i < NB; i += 256) lcnt[i] = 0;
    __syncthreads();
    const long long total = 2LL * E;
    const long long stride = (long long)gridDim.x * blockDim.x;
    for (long long e = (long long)blockIdx.x * blockDim.x + threadIdx.x;
         e < total; e += stride) {
        const void* idx = up; long long ee = e;
        if (ee >= E) { idx = down; ee -= E; }
        int dst = load_idx(idx, E + ee, is64);
        atomicAdd(&lcnt[dst >> NPB_SHIFT], 1);
    }
    __syncthreads();
    for (int i = threadIdx.x; i < NB; i += 256)
        if (lcnt[i]) atomicAdd(&fineCnt[i], lcnt[i]);
}

// ---- phase 2: exclusive scan -> fine offsets + padded cursors ----
__global__ __launch_bounds__(1024) void scan_kernel(
        const int* __restrict__ fineCnt, int* __restrict__ fineOff,
        int* __restrict__ gcursor, int NB) {
    __shared__ int sums[1024];
    const int tid = threadIdx.x;
    const int chunk = (NB + 1023) / 1024;
    const int start = tid * chunk;
    const int end = min(start + chunk, NB);
    int s = 0;
    for (int i = start; i < end; i++) s += fineCnt[i];
    sums[tid] = s;
    __syncthreads();
    for (int off = 1; off < 1024; off <<= 1) {
        int t = (tid >= off) ? sums[tid - off] : 0;
        __syncthreads();
        sums[tid] += t;
        __syncthreads();
    }
    int run = (tid == 0) ? 0 : sums[tid - 1];
    for (int i = start; i < end; i++) {
        fineOff[i] = run;
        gcursor[i * CURPAD] = run;
        run += fineCnt[i];
    }
    if (tid == 1023) fineOff[NB] = run;
}

// ---- phase 3: scatter rec = (src<<6)|dst_local into exact bucket bins ----
// Per-block two-pass: LDS count (dst-only read), reserve contiguous runs via
// one padded global atomic per (block,bucket), then write runs.
__global__ __launch_bounds__(256) void scatter_part_kernel(
        const void* __restrict__ up, const void* __restrict__ down,
        int* __restrict__ gcursor, unsigned* __restrict__ recB,
        const int* __restrict__ flag, int E, int NB) {
    extern __shared__ int lds[];
    int* cnt = lds;        // [NB]
    int* base = lds + NB;  // [NB]
    const int is64 = *flag;
    const long long total = 2LL * E;
    const long long cs = (long long)blockIdx.x * CHUNK;
    if (cs >= total) return;
    const long long ce = min(total, cs + (long long)CHUNK);

    for (int i = threadIdx.x; i < NB; i += 256) cnt[i] = 0;
    __syncthreads();
    for (long long e = cs + threadIdx.x; e < ce; e += 256) {
        const void* idx = up; long long ee = e;
        if (ee >= E) { idx = down; ee -= E; }
        int dst = load_idx(idx, E + ee, is64);
        atomicAdd(&cnt[dst >> NPB_SHIFT], 1);
    }
    __syncthreads();
    for (int i = threadIdx.x; i < NB; i += 256) {
        int c = cnt[i];
        base[i] = c ? atomicAdd(&gcursor[i * CURPAD], c) : 0;
        cnt[i] = 0;  // reuse as local cursor
    }
    __syncthreads();
    for (long long e = cs + threadIdx.x; e < ce; e += 256) {
        const void* idx = up; long long ee = e;
        if (ee >= E) { idx = down; ee -= E; }
        int src = load_idx(idx, ee, is64);
        int dst = load_idx(idx, E + ee, is64);
        int b = dst >> NPB_SHIFT;
        int pos = base[b] + atomicAdd(&cnt[b], 1);
        recB[pos] = ((unsigned)src << NPB_SHIFT) | (unsigned)(dst & (NPB - 1));
    }
}

// ---- phase 4: per-bucket sort by (dl MAJOR, slab minor) + 4-way merge-walk ----
__global__ __launch_bounds__(256) void bucket_gather_kernel(
        const float* __restrict__ x, const int* __restrict__ fineOff,
        const unsigned* __restrict__ recB, float* __restrict__ out,
        int N, int sshift) {
    __shared__ unsigned sorted[CH];       // 32 KB
    __shared__ int cnt[NBIN];             // 4 KB
    __shared__ int binoff[NBIN + 1];      // 4 KB
    __shared__ int cursor[NBIN];          // 4 KB
    __shared__ int wsum[4];

    const int b = blockIdx.x;
    const int tid = threadIdx.x;
    const int g = tid >> 4;   // group 0..15 (owns dls 4g..4g+3)
    const int q = tid & 15;   // quad within row
    const int lane = tid & 63;
    const int wv = tid >> 6;
    const int beg = fineOff[b], end = fineOff[b + 1];

    float4 acc0 = make_float4(0.f, 0.f, 0.f, 0.f);
    float4 acc1 = acc0, acc2 = acc0, acc3 = acc0;

    for (int cs = beg; cs < end; cs += CH) {
        const int m = min(CH, end - cs);
        #pragma unroll
        for (int i = 0; i < NBIN / 256; i++) cnt[tid + 256 * i] = 0;
        __syncthreads();
        for (int i = tid; i < m; i += 256) {
            unsigned p = recB[cs + i];
            int key = ((int)(p & (NPB - 1)) << 4) | (int)((p >> NPB_SHIFT) >> sshift);
            atomicAdd(&cnt[key], 1);
        }
        __syncthreads();
        {   // block exclusive scan over NBIN bins (4 bins/thread)
            int b0 = cnt[4 * tid], b1 = cnt[4 * tid + 1];
            int b2 = cnt[4 * tid + 2], b3 = cnt[4 * tid + 3];
            int tsum = b0 + b1 + b2 + b3;
            int inc = tsum;
            #pragma unroll
            for (int off = 1; off < 64; off <<= 1) {
                int t = __shfl_up(inc, off, 64);
                if (lane >= off) inc += t;
            }
            if (lane == 63) wsum[wv] = inc;
            __syncthreads();
            int wbase = 0;
            #pragma unroll
            for (int w = 0; w < 4; w++) wbase += (w < wv) ? wsum[w] : 0;
            int excl = wbase + inc - tsum;
            binoff[4 * tid] = excl; cursor[4 * tid] = excl; excl += b0;
            binoff[4 * tid + 1] = excl; cursor[4 * tid + 1] = excl; excl += b1;
            binoff[4 * tid + 2] = excl; cursor[4 * tid + 2] = excl; excl += b2;
            binoff[4 * tid + 3] = excl; cursor[4 * tid + 3] = excl; excl += b3;
            if (tid == 255) binoff[NBIN] = excl;
        }
        __syncthreads();
        for (int i = tid; i < m; i += 256) {
            unsigned p = recB[cs + i];
            int key = ((int)(p & (NPB - 1)) << 4) | (int)((p >> NPB_SHIFT) >> sshift);
            int pos = atomicAdd(&cursor[key], 1);
            sorted[pos] = p;
        }
        __syncthreads();
        {   // 4-way merge-walk: one record from each dl-range per iteration.
            // Ranges are slab-sorted; all groups advance in near-lockstep ->
            // sliding x window. 4 independent row-loads in flight, direct adds.
            int e0 = binoff[(4 * g + 0) << 4], r0 = binoff[(4 * g + 1) << 4];
            int e1 = r0,                       r1 = binoff[(4 * g + 2) << 4];
            int e2 = r1,                       r2 = binoff[(4 * g + 3) << 4];
            int e3 = r2,                       r3 = binoff[(4 * g + 4) << 4];
            while ((e0 < r0) | (e1 < r1) | (e2 < r2) | (e3 < r3)) {
                const bool a0 = e0 < r0, a1 = e1 < r1, a2 = e2 < r2, a3 = e3 < r3;
                float4 v0, v1, v2, v3;
                if (a0) { unsigned p = sorted[e0];
                    v0 = *(const float4*)(x + ((long long)(p >> NPB_SHIFT)) * D + q * 4); }
                if (a1) { unsigned p = sorted[e1];
                    v1 = *(const float4*)(x + ((long long)(p >> NPB_SHIFT)) * D + q * 4); }
                if (a2) { unsigned p = sorted[e2];
                    v2 = *(const float4*)(x + ((long long)(p >> NPB_SHIFT)) * D + q * 4); }
                if (a3) { unsigned p = sorted[e3];
                    v3 = *(const float4*)(x + ((long long)(p >> NPB_SHIFT)) * D + q * 4); }
                if (a0) { acc0.x += v0.x; acc0.y += v0.y; acc0.z += v0.z; acc0.w += v0.w; e0++; }
                if (a1) { acc1.x += v1.x; acc1.y += v1.y; acc1.z += v1.z; acc1.w += v1.w; e1++; }
                if (a2) { acc2.x += v2.x; acc2.y += v2.y; acc2.z += v2.z; acc2.w += v2.w; e2++; }
                if (a3) { acc3.x += v3.x; acc3.y += v3.y; acc3.z += v3.z; acc3.w += v3.w; e3++; }
            }
        }
        __syncthreads();  // done reading sorted before next chunk reuses LDS
    }

    const int node0 = b * NPB + 4 * g;
    if (node0 + 0 < N) *(float4*)(out + (long long)(node0 + 0) * D + q * 4) = acc0;
    if (node0 + 1 < N) *(float4*)(out + (long long)(node0 + 1) * D + q * 4) = acc1;
    if (node0 + 2 < N) *(float4*)(out + (long long)(node0 + 2) * D + q * 4) = acc2;
    if (node0 + 3 < N) *(float4*)(out + (long long)(node0 + 3) * D + q * 4) = acc3;
}

// ---- fallback: direct fp32 atomics (R1), needs no workspace ----
__global__ __launch_bounds__(256) void scatter_add_kernel(
        const float* __restrict__ x, const void* __restrict__ up_idx,
        const void* __restrict__ down_idx, float* __restrict__ out,
        const int* __restrict__ dtype_flag, int num_edges) {
    const int is64 = *dtype_flag;
    const long long total = 2LL * num_edges * Q;
    const long long stride = (long long)gridDim.x * blockDim.x;
    for (long long t = (long long)blockIdx.x * blockDim.x + threadIdx.x;
         t < total; t += stride) {
        const int quad = (int)(t & (Q - 1));
        long long eg = t >> 4;
        const void* idx = up_idx;
        if (eg >= num_edges) { idx = down_idx; eg -= num_edges; }
        int src = load_idx(idx, eg, is64);
        int dst = load_idx(idx, num_edges + eg, is64);
        const float4 v = *(const float4*)(x + (long long)src * D + quad * 4);
        float* o = out + (long long)dst * D + quad * 4;
        unsafeAtomicAdd(o + 0, v.x);
        unsafeAtomicAdd(o + 1, v.y);
        unsafeAtomicAdd(o + 2, v.z);
        unsafeAtomicAdd(o + 3, v.w);
    }
}

extern "C" void kernel_launch(void* const* d_in, const int* in_sizes, int n_in,
                              void* d_out, int out_size, void* d_ws, size_t ws_size,
                              hipStream_t stream) {
    const float* x = (const float*)d_in[0];
    const void* up_idx = d_in[1];
    const void* down_idx = d_in[2];
    float* out = (float*)d_out;

    const int E = in_sizes[1] / 2;   // [2, E]
    const int N = out_size / D;      // [N, 64]
    const int NB = (N + NPB - 1) / NPB;
    const long long Etot = 2LL * E;

    // slab shift: smallest s with (N-1)>>s < SLABS
    int sshift = 0;
    while (((unsigned)(N - 1) >> sshift) >= SLABS) sshift++;

    // ws layout (ints): flag(64) | fineCnt[NB] | fineOff[NB+1]+pad | gcursor[NB*CURPAD] | recB[Etot]
    int* ws_i = (int*)d_ws;
    int* flag = ws_i;
    int* fineCnt = ws_i + 64;
    int* fineOff = fineCnt + NB;
    int* gcursor = fineOff + NB + 1 + 15;
    unsigned* recB = (unsigned*)(gcursor + (long long)NB * CURPAD);
    const size_t ws_need = (size_t)(64 + NB + NB + 16 +
                                    (long long)NB * CURPAD + Etot) * 4 + 64;

    detect_idx_dtype<<<1, 64, 0, stream>>>((const int*)up_idx, flag);

    if (ws_size >= ws_need && E >= 64 && N >= 1 &&
        N <= (1 << 17) && Etot < (1LL << 31)) {
        hipMemsetAsync(fineCnt, 0, (size_t)NB * sizeof(int), stream);
        hist_kernel<<<2048, 256, NB * sizeof(int), stream>>>(
            up_idx, down_idx, fineCnt, flag, E, NB);
        scan_kernel<<<1, 1024, 0, stream>>>(fineCnt, fineOff, gcursor, NB);
        const int sblocks = (int)((Etot + CHUNK - 1) / CHUNK);
        scatter_part_kernel<<<sblocks, 256, 2 * NB * sizeof(int), stream>>>(
            up_idx, down_idx, gcursor, recB, flag, E, NB);
        bucket_gather_kernel<<<NB, 256, 0, stream>>>(x, fineOff, recB, out, N, sshift);
    } else {
        hipMemsetAsync(d_out, 0, (size_t)out_size * sizeof(float), stream);
        scatter_add_kernel<<<8192, 256, 0, stream>>>(x, up_idx, down_idx, out, flag, E);
    }
}